// Round 4
// baseline (199.083 us; speedup 1.0000x reference)
//
#include <hip/hip_runtime.h>

#define HWSZ (512 * 512)          // H*W
#define NPIX (8 * HWSZ)           // B*H*W = 2,097,152
#define PPT  8                    // pixels per thread
#define NBLK (NPIX / PPT / 256)   // 1024 blocks
#define LOG32 3.4657359027997265f // log(8) + log(4)

// Streaming formulation (no max-subtraction: logits ~ N(0,1), exp safe in
// fp32). Per pixel with target t:
//   loss_pix = 3*log(Z) - log(E0) - log(E1) - l_t + log(32)
// Z = sum exp(l_c), E0 = t's half-sum (8ch), E1 = t's quarter-sum (4ch).
// 8 px/thread -> 32 independent dwordx4 loads in flight (2x ILP vs R2's 16)
// to attack memory latency; all state in named float4s (no indexed arrays,
// which R0 showed get demoted to LDS/scratch).
__global__ __launch_bounds__(256) void hier_loss_main(
    const float* __restrict__ logits,
    const int* __restrict__ target,
    float* __restrict__ partial)
{
    const int tid = blockIdx.x * blockDim.x + threadIdx.x;
    const long p0 = (long)tid * PPT;        // 8 consecutive pixels per thread
    const int b  = (int)(p0 >> 18);         // HWSZ = 2^18
    const int hw = (int)(p0 & (HWSZ - 1));  // never crosses batch boundary
    const float* base = logits + (long)b * 16 * HWSZ + hw;

    const int4 ta = *(const int4*)(target + p0);
    const int4 tb = *(const int4*)(target + p0 + 4);

    float4 qa0 = {0,0,0,0}, qa1 = {0,0,0,0}, qa2 = {0,0,0,0}, qa3 = {0,0,0,0};
    float4 qb0 = {0,0,0,0}, qb1 = {0,0,0,0}, qb2 = {0,0,0,0}, qb3 = {0,0,0,0};
    float4 lta = {0,0,0,0}, ltb = {0,0,0,0};

#define DO_CH(c, qa, qb)                                              \
    {                                                                 \
        float4 va = *(const float4*)(base + (long)(c) * HWSZ);        \
        float4 vb = *(const float4*)(base + (long)(c) * HWSZ + 4);    \
        lta.x = (ta.x == (c)) ? va.x : lta.x;                         \
        lta.y = (ta.y == (c)) ? va.y : lta.y;                         \
        lta.z = (ta.z == (c)) ? va.z : lta.z;                         \
        lta.w = (ta.w == (c)) ? va.w : lta.w;                         \
        ltb.x = (tb.x == (c)) ? vb.x : ltb.x;                         \
        ltb.y = (tb.y == (c)) ? vb.y : ltb.y;                         \
        ltb.z = (tb.z == (c)) ? vb.z : ltb.z;                         \
        ltb.w = (tb.w == (c)) ? vb.w : ltb.w;                         \
        qa.x += __expf(va.x);  qa.y += __expf(va.y);                  \
        qa.z += __expf(va.z);  qa.w += __expf(va.w);                  \
        qb.x += __expf(vb.x);  qb.y += __expf(vb.y);                  \
        qb.z += __expf(vb.z);  qb.w += __expf(vb.w);                  \
    }

    DO_CH(0,  qa0, qb0) DO_CH(1,  qa0, qb0) DO_CH(2,  qa0, qb0) DO_CH(3,  qa0, qb0)
    DO_CH(4,  qa1, qb1) DO_CH(5,  qa1, qb1) DO_CH(6,  qa1, qb1) DO_CH(7,  qa1, qb1)
    DO_CH(8,  qa2, qb2) DO_CH(9,  qa2, qb2) DO_CH(10, qa2, qb2) DO_CH(11, qa2, qb2)
    DO_CH(12, qa3, qb3) DO_CH(13, qa3, qb3) DO_CH(14, qa3, qb3) DO_CH(15, qa3, qb3)
#undef DO_CH

    float acc = 0.0f;
#define PIX(g0, g1, g2, g3, ltv, comp, t)                                    \
    {                                                                        \
        const float a0 = g0.comp, a1 = g1.comp, a2 = g2.comp, a3 = g3.comp;  \
        const float hA = a0 + a1, hB = a2 + a3;                              \
        const float Z  = hA + hB;                                            \
        const float E0 = ((t) & 8) ? hB : hA;                                \
        const float ea = ((t) & 4) ? a1 : a0;                                \
        const float eb = ((t) & 4) ? a3 : a2;                                \
        const float E1 = ((t) & 8) ? eb : ea;                                \
        acc += 3.0f * __logf(Z) - __logf(E0) - __logf(E1) - ltv.comp + LOG32;\
    }
    PIX(qa0, qa1, qa2, qa3, lta, x, ta.x) PIX(qa0, qa1, qa2, qa3, lta, y, ta.y)
    PIX(qa0, qa1, qa2, qa3, lta, z, ta.z) PIX(qa0, qa1, qa2, qa3, lta, w, ta.w)
    PIX(qb0, qb1, qb2, qb3, ltb, x, tb.x) PIX(qb0, qb1, qb2, qb3, ltb, y, tb.y)
    PIX(qb0, qb1, qb2, qb3, ltb, z, tb.z) PIX(qb0, qb1, qb2, qb3, ltb, w, tb.w)
#undef PIX

    // wave (64-lane) shuffle reduce -> LDS -> one plain store per block
    const int lane = threadIdx.x & 63;
    const int wave = threadIdx.x >> 6;
#pragma unroll
    for (int off = 32; off > 0; off >>= 1)
        acc += __shfl_down(acc, off, 64);

    __shared__ float red[4];
    if (lane == 0) red[wave] = acc;
    __syncthreads();
    if (threadIdx.x == 0)
        partial[blockIdx.x] = (red[0] + red[1]) + (red[2] + red[3]);
}

// Single-block final reduce: NBLK partials -> scalar. Plain store to d_out,
// so no zero-init / memset needed anywhere.
__global__ __launch_bounds__(256) void hier_loss_reduce(
    const float* __restrict__ partial,
    float* __restrict__ out)
{
    float s = 0.0f;
#pragma unroll
    for (int i = 0; i < NBLK / 256; ++i)
        s += partial[threadIdx.x + i * 256];

    const int lane = threadIdx.x & 63;
    const int wave = threadIdx.x >> 6;
#pragma unroll
    for (int off = 32; off > 0; off >>= 1)
        s += __shfl_down(s, off, 64);

    __shared__ float red[4];
    if (lane == 0) red[wave] = s;
    __syncthreads();
    if (threadIdx.x == 0)
        out[0] = ((red[0] + red[1]) + (red[2] + red[3])) * (1.0f / (float)NPIX);
}

extern "C" void kernel_launch(void* const* d_in, const int* in_sizes, int n_in,
                              void* d_out, int out_size, void* d_ws, size_t ws_size,
                              hipStream_t stream) {
    const float* logits = (const float*)d_in[0];
    const int*   target = (const int*)d_in[1];
    float* out     = (float*)d_out;
    float* partial = (float*)d_ws;   // NBLK floats, fully overwritten each call

    hier_loss_main<<<NBLK, 256, 0, stream>>>(logits, target, partial);
    hier_loss_reduce<<<1, 256, 0, stream>>>(partial, out);
}